// Round 2
// baseline (1217.814 us; speedup 1.0000x reference)
//
#include <hip/hip_runtime.h>

// PWC-Net FunctionCorrelation (max_disp=4 -> 81 channels) + LeakyReLU(0.1)
// feat1, feat2: [8, 256, 80, 160] fp32 NCHW. out: [8, 81, 80, 160] fp32.
// out[n, dy*9+dx, y, x] = leaky((1/256) * sum_c f1[n,c,y,x]*f2pad[n,c,y+dy,x+dx])
//
// R1 design: tile 4x32 px, 800 blocks of 288 threads (waves 0-3 = dy pairs
// {0,1}..{6,7} split by lane-half h; half-wave 4 = dy 8). f1 read direct from
// global (L1/L2 dedups the 9x intra-block reuse); f2 staged through a
// register->LDS double-buffered pipeline (one barrier per channel chunk).

constexpr int MAXD = 4;
constexpr int N_ = 8, C_ = 256, H_ = 80, W_ = 160, HW_ = H_ * W_;
constexpr int TH = 4, TW = 32;
constexpr int CK = 8;                      // channels per chunk
constexpr int F2H = TH + 2 * MAXD;         // 12
constexpr int F2W = TW + 2 * MAXD;         // 40 (unpadded: quad-linear b128 reads)
constexpr int CHUNK_ELEMS = CK * F2H * F2W;  // 3840 words / buffer
constexpr int NTHR = 288;
constexpr int NLOAD = (CHUNK_ELEMS + NTHR - 1) / NTHR;  // 14
constexpr int TILES_X = W_ / TW;           // 5
constexpr int TILES_Y = H_ / TH;           // 20
constexpr int NCHUNK = C_ / CK;            // 32

__global__ __launch_bounds__(NTHR, 4)
void corr_leaky_kernel(const float* __restrict__ f1,
                       const float* __restrict__ f2,
                       float* __restrict__ out)
{
    __shared__ float s2[2][CHUNK_ELEMS];   // 30720 B

    const int t    = threadIdx.x;
    const int wv   = t >> 6;
    const int lane = t & 63;
    const int h    = lane >> 5;            // which dy of the pair
    const int l5   = lane & 31;
    const int r    = l5 >> 3;              // tile row 0..3
    const int xg   = l5 & 7;               // x-quad 0..7
    const int dy   = (wv < 4) ? (2 * wv + h) : 8;  // wv==4: threads 256..287, h==0

    const int bid = blockIdx.x;
    const int n   = bid / (TILES_X * TILES_Y);
    const int tr  = bid % (TILES_X * TILES_Y);
    const int y0  = (tr / TILES_X) * TH;
    const int x0  = (tr % TILES_X) * TW;

    const float* f1n = f1 + (size_t)n * C_ * HW_;
    const float* f2n = f2 + (size_t)n * C_ * HW_;

    // ---- staging address precompute: pattern repeats every 5 j's (+3 channels) ----
    // flat LDS index i = t + 288*j; lcm(288, 480) = 1440 = 5*288 = 3*480.
    int  goff[5];   // element offset in f2n (chunk base c0=0)
    int  loff[5];   // word offset in one s2 buffer
    bool inb[5];
#pragma unroll
    for (int jj = 0; jj < 5; ++jj) {
        const int i0  = t + NTHR * jj;         // < 1440
        const int cc0 = i0 / (F2H * F2W);
        const int rem = i0 % (F2H * F2W);
        const int ly  = rem / F2W;
        const int lx  = rem % F2W;
        const int gy  = y0 + ly - MAXD;
        const int gx  = x0 + lx - MAXD;
        const bool ok = ((unsigned)gy < (unsigned)H_) && ((unsigned)gx < (unsigned)W_);
        inb[jj]  = ok;
        goff[jj] = cc0 * HW_ + (ok ? (gy * W_ + gx) : 0);
        loff[jj] = i0;
    }
    const bool has14 = (t < CHUNK_ELEMS - (NLOAD - 1) * NTHR);  // t < 96

    float acc[9][4];
#pragma unroll
    for (int dx = 0; dx < 9; ++dx)
#pragma unroll
        for (int p = 0; p < 4; ++p) acc[dx][p] = 0.0f;

    const int rg = r + dy;                      // f2-tile row, 0..11
    const float* f1row = f1n + (y0 + r) * W_ + x0 + 4 * xg;

    float st[NLOAD];

    // ---- prologue: stage chunk 0 ----
#pragma unroll
    for (int j = 0; j < NLOAD; ++j) {
        const int jj = j % 5, cyc = j / 5;
        const bool ok = inb[jj] && (j < NLOAD - 1 || has14);
        st[j] = ok ? f2n[goff[jj] + 3 * cyc * HW_] : 0.0f;
    }
#pragma unroll
    for (int j = 0; j < NLOAD; ++j) {
        const int jj = j % 5, cyc = j / 5;
        if (j < NLOAD - 1 || has14) s2[0][loff[jj] + 1440 * cyc] = st[j];
    }
    __syncthreads();

    // ---- pipelined main loop: one barrier per chunk ----
    for (int k = 0; k < NCHUNK; ++k) {
        const int p  = k & 1;
        const int c0 = k * CK;

        // a-loads for chunk k (issued first -> waited progressively in FMA loop)
        float4 a[CK];
#pragma unroll
        for (int cc = 0; cc < CK; ++cc)
            a[cc] = *(const float4*)(f1row + (size_t)(c0 + cc) * HW_);

        // prefetch chunk k+1 f2 -> regs (younger vmcnt entries; waited only at LDS write)
        if (k + 1 < NCHUNK) {
            const int cb = c0 + CK;
#pragma unroll
            for (int j = 0; j < NLOAD; ++j) {
                const int jj = j % 5, cyc = j / 5;
                const bool ok = inb[jj] && (j < NLOAD - 1 || has14);
                st[j] = ok ? f2n[goff[jj] + (cb + 3 * cyc) * HW_] : 0.0f;
            }
        }

        // compute chunk k from s2[p]
        const float* buf = s2[p];
#pragma unroll
        for (int cc = 0; cc < CK; ++cc) {
            const float* bp = buf + cc * (F2H * F2W) + rg * F2W + 4 * xg;
            const float4 b0 = *(const float4*)bp;
            const float4 b1 = *(const float4*)(bp + 4);
            const float4 b2 = *(const float4*)(bp + 8);
            const float aa[4]  = {a[cc].x, a[cc].y, a[cc].z, a[cc].w};
            const float bb[12] = {b0.x, b0.y, b0.z, b0.w,
                                  b1.x, b1.y, b1.z, b1.w,
                                  b2.x, b2.y, b2.z, b2.w};
#pragma unroll
            for (int dx = 0; dx < 9; ++dx)
#pragma unroll
                for (int q = 0; q < 4; ++q)
                    acc[dx][q] = fmaf(aa[q], bb[q + dx], acc[dx][q]);
        }

        // write prefetched chunk k+1 into the other buffer
        if (k + 1 < NCHUNK) {
            float* nb = s2[1 - p];
#pragma unroll
            for (int j = 0; j < NLOAD; ++j) {
                const int jj = j % 5, cyc = j / 5;
                if (j < NLOAD - 1 || has14) nb[loff[jj] + 1440 * cyc] = st[j];
            }
        }
        __syncthreads();
    }

    // ---- epilogue: scale, LeakyReLU, float4 stores ----
    const float inv_c = 1.0f / (float)C_;
    const int y  = y0 + r;
    const int xb = x0 + 4 * xg;
#pragma unroll
    for (int dx = 0; dx < 9; ++dx) {
        float4 v;
        const float e0 = acc[dx][0] * inv_c;
        const float e1 = acc[dx][1] * inv_c;
        const float e2 = acc[dx][2] * inv_c;
        const float e3 = acc[dx][3] * inv_c;
        v.x = e0 > 0.0f ? e0 : 0.1f * e0;
        v.y = e1 > 0.0f ? e1 : 0.1f * e1;
        v.z = e2 > 0.0f ? e2 : 0.1f * e2;
        v.w = e3 > 0.0f ? e3 : 0.1f * e3;
        const int ch = dy * 9 + dx;
        const size_t off = ((size_t)(n * 81 + ch) * H_ + y) * W_ + xb;
        *(float4*)&out[off] = v;
    }
}

extern "C" void kernel_launch(void* const* d_in, const int* in_sizes, int n_in,
                              void* d_out, int out_size, void* d_ws, size_t ws_size,
                              hipStream_t stream) {
    const float* f1 = (const float*)d_in[0];
    const float* f2 = (const float*)d_in[1];
    float* out = (float*)d_out;
    const int nblocks = N_ * TILES_X * TILES_Y;  // 800
    corr_leaky_kernel<<<dim3(nblocks), dim3(NTHR), 0, stream>>>(f1, f2, out);
}

// Round 3
// 417.950 us; speedup vs baseline: 2.9138x; 2.9138x over previous
//
#include <hip/hip_runtime.h>
#include <stdint.h>

// PWC-Net FunctionCorrelation (max_disp=4 -> 81 channels) + LeakyReLU(0.1)
// feat1, feat2: [8, 256, 80, 160] fp32 NCHW. out: [8, 81, 80, 160] fp32.
//
// R2: tile 4x32, 288 thr (9 half-wave dy groups), 800 blocks, XCD-swizzled
// (bid&7 = image). Staging via __builtin_amdgcn_global_load_lds (16B units,
// no VGPR roundtrip), LDS double-buffered, ONE barrier per channel chunk.
// OOB halo = exec-masked loads over pre-zeroed LDS.

constexpr int MAXD = 4;
constexpr int N_ = 8, C_ = 256, H_ = 80, W_ = 160, HW_ = H_ * W_;
constexpr int TH = 4, TW = 32;
constexpr int CK = 8;                    // channels per chunk
constexpr int F2H = TH + 2 * MAXD;       // 12
constexpr int F2W = TW + 2 * MAXD;       // 40
constexpr int S1W = CK * TH * TW;        // 1024 words
constexpr int S2W = CK * F2H * F2W;      // 3840 words
constexpr int BUFW = S1W + S2W;          // 4864 words = 19456 B per buffer
constexpr int UNITS = BUFW / 4;          // 1216 16-byte units per chunk
constexpr int NTHR = 288;
constexpr int TILES_X = W_ / TW;         // 5
constexpr int TILES_Y = H_ / TH;         // 20
constexpr int NCHUNK = C_ / CK;          // 32

__device__ __forceinline__ void load16_lds(const float* g, float* l) {
    __builtin_amdgcn_global_load_lds(
        (const __attribute__((address_space(1))) uint8_t*)(const void*)g,
        (__attribute__((address_space(3))) uint8_t*)(void*)l,
        16, 0, 0);
}

__global__ __launch_bounds__(NTHR)
void corr_leaky_kernel(const float* __restrict__ f1,
                       const float* __restrict__ f2,
                       float* __restrict__ out)
{
    __shared__ float sbuf[2 * BUFW];     // 38912 B

    const int t    = threadIdx.x;
    const int wv   = t >> 6;             // 0..4 (wave 4 is a half wave)
    const int lane = t & 63;
    const int h    = lane >> 5;
    const int l5   = lane & 31;
    const int r    = l5 >> 3;            // tile row 0..3
    const int xg   = l5 & 7;             // x-quad 0..7
    const int dy   = (wv < 4) ? (2 * wv + h) : 8;

    // XCD swizzle: consecutive bids on one XCD share an image -> halo hits L2
    const int bid = blockIdx.x;
    const int n   = bid & 7;
    const int tr  = bid >> 3;            // 0..99
    const int y0  = (tr / TILES_X) * TH;
    const int x0  = (tr % TILES_X) * TW;

    const float* f1n = f1 + (size_t)n * C_ * HW_;
    const float* f2n = f2 + (size_t)n * C_ * HW_;

    // ---- staging precompute: unit u = t + 288*j, j = 0..4 ----
    // LDS word offset of unit u is exactly 4*u (natural row-major concat of
    // s1[ch][4][32] then s2[ch][12][40]), matching the HW's base+lane*16 rule.
    const float* gp[5];
    unsigned msk = 0;
#pragma unroll
    for (int j = 0; j < 5; ++j) {
        const int u = t + NTHR * j;
        gp[j] = f1n;                                  // dummy for inactive
        if (u < UNITS) {
            if (u < S1W / 4) {                        // f1 region: 256 units
                const int ch = u >> 5, rr = (u >> 3) & 3, pp = u & 7;
                gp[j] = f1n + ch * HW_ + (y0 + rr) * W_ + x0 + 4 * pp;
                msk |= 1u << j;
            } else {                                  // f2 region: 960 units
                const int v  = u - S1W / 4;
                const int ch = v / 120, v2 = v % 120;
                const int rr = v2 / 10, pp = v2 % 10;
                const int gy = y0 + rr - MAXD;
                const int gx = x0 + 4 * pp - MAXD;    // 16B-aligned always
                const bool ok = ((unsigned)gy < (unsigned)H_) &&
                                ((unsigned)gx < (unsigned)W_);
                gp[j] = f2n + ch * HW_ + (ok ? gy * W_ + gx : 0);
                if (ok) msk |= 1u << j;
            }
        }
    }

    // ---- zero both buffers once: masked (OOB) units stay zero forever ----
    for (int i = t; i < 2 * BUFW; i += NTHR) sbuf[i] = 0.0f;
    __syncthreads();

    // issue chunk-0 loads; barrier drains vmcnt -> chunk 0 resident
#define STAGE(k, p)                                                          \
    {                                                                        \
        const size_t cadv = (size_t)(k) * CK * HW_;                          \
        float* lb = sbuf + (p) * BUFW + 256 * wv;  /* wave-uniform base */   \
        _Pragma("unroll")                                                    \
        for (int j = 0; j < 4; ++j)                                          \
            if ((msk >> j) & 1) load16_lds(gp[j] + cadv, lb + 1152 * j);     \
        if (wv == 0 && ((msk >> 4) & 1))                                     \
            load16_lds(gp[4] + cadv, lb + 1152 * 4);                         \
    }

    STAGE(0, 0);
    __syncthreads();

    float acc[9][4];
#pragma unroll
    for (int dx = 0; dx < 9; ++dx)
#pragma unroll
        for (int q = 0; q < 4; ++q) acc[dx][q] = 0.0f;

    const int rg = r + dy;               // f2-tile row 0..11

    int p = 0;
    for (int k = 0; k < NCHUNK; ++k) {
        // issue next chunk's loads first: they age through the compute phase,
        // so the compiler's vmcnt(0) drain before the barrier is nearly free
        if (k + 1 < NCHUNK) STAGE(k + 1, 1 - p);

        const float* bp0 = sbuf + p * BUFW;
#pragma unroll
        for (int cc = 0; cc < CK; ++cc) {
            const float4 a4 = *(const float4*)(bp0 + 128 * cc + 32 * r + 4 * xg);
            const float* bb = bp0 + S1W + 480 * cc + 40 * rg + 4 * xg;
            const float4 b0 = *(const float4*)bb;
            const float4 b1 = *(const float4*)(bb + 4);
            const float4 b2 = *(const float4*)(bb + 8);
            const float aa[4]  = {a4.x, a4.y, a4.z, a4.w};
            const float bw[12] = {b0.x, b0.y, b0.z, b0.w,
                                  b1.x, b1.y, b1.z, b1.w,
                                  b2.x, b2.y, b2.z, b2.w};
#pragma unroll
            for (int dx = 0; dx < 9; ++dx)
#pragma unroll
                for (int q = 0; q < 4; ++q)
                    acc[dx][q] = fmaf(aa[q], bw[q + dx], acc[dx][q]);
        }
        __syncthreads();
        p ^= 1;
    }

    // ---- epilogue: scale, LeakyReLU, coalesced float4 stores ----
    const float inv_c = 1.0f / (float)C_;
    const int y  = y0 + r;
    const int xb = x0 + 4 * xg;
#pragma unroll
    for (int dx = 0; dx < 9; ++dx) {
        const float e0 = acc[dx][0] * inv_c;
        const float e1 = acc[dx][1] * inv_c;
        const float e2 = acc[dx][2] * inv_c;
        const float e3 = acc[dx][3] * inv_c;
        float4 v;
        v.x = e0 > 0.0f ? e0 : 0.1f * e0;
        v.y = e1 > 0.0f ? e1 : 0.1f * e1;
        v.z = e2 > 0.0f ? e2 : 0.1f * e2;
        v.w = e3 > 0.0f ? e3 : 0.1f * e3;
        const int ch = dy * 9 + dx;
        const size_t off = ((size_t)(n * 81 + ch) * H_ + y) * W_ + xb;
        *(float4*)&out[off] = v;
    }
}

extern "C" void kernel_launch(void* const* d_in, const int* in_sizes, int n_in,
                              void* d_out, int out_size, void* d_ws, size_t ws_size,
                              hipStream_t stream) {
    const float* f1 = (const float*)d_in[0];
    const float* f2 = (const float*)d_in[1];
    float* out = (float*)d_out;
    const int nblocks = N_ * TILES_X * TILES_Y;  // 800
    corr_leaky_kernel<<<dim3(nblocks), dim3(NTHR), 0, stream>>>(f1, f2, out);
}

// Round 5
// 324.798 us; speedup vs baseline: 3.7495x; 1.2868x over previous
//
#include <hip/hip_runtime.h>
#include <stdint.h>

// PWC-Net FunctionCorrelation (81 disp) + LeakyReLU(0.1) via bf16 MFMA.
// out[n, dy*9+dx, y, x] = leaky((1/256) Σ_c f1[n,c,y,x] f2p[n,c,y+dy-4,x+dx-4])
//
// Banded-GEMM: per (block y-row wave, dy): D[16m][16n] = A·B^T, K=256.
//   A[m][k] = f1[c0+k, y, x0+m]          (m 0..15; outputs use m<8)
//   B[n][k] = f2p[c0+k, y+dy-4, x0-4+n]  (n 0..15)
//   out(x=x0+m, dx=n-m) valid for m<8, 0<=n-m<=8  (72/256 of tile)
// Block: 8y x 8x outputs, 512 thr (8 waves, wave=y), 8 K-chunks of 32,
// LDS double-buffered bf16 staging, XCD-pinned image (bid&7) + chunk phase.
//
// R4 fix: B LOADS had "+ 4*tq" on top of offB[tq] which already includes
// xq = xB0 + 4*tq -> n-columns 4..7 / 12..15 read from x+4 (absmax 0.325).

constexpr int MAXD = 4;
constexpr int N_ = 8, C_ = 256, H_ = 80, W_ = 160, HW_ = H_ * W_;
constexpr int YT = 8, XT = 8;
constexpr int KC = 32;                  // channels per chunk
constexpr int NCH = C_ / KC;            // 8
constexpr int KLINE = 20;               // words per k-line: 16 data (32 bf16) + 4 pad
constexpr int ROWW  = 16 * KLINE + 8;   // 328 words per m/n-row block (+8 pad)
constexpr int AW    = YT * ROWW;        // 2624 words
constexpr int BWRD  = 16 * ROWW;        // 5248 words
constexpr int BUFW  = AW + BWRD;        // 7872 words = 31488 B per buffer
constexpr int NTHR  = 512;

typedef __attribute__((ext_vector_type(8))) short  frag_ab;   // 8 bf16
typedef __attribute__((ext_vector_type(4))) float  frag_cd;   // 4 fp32

__device__ __forceinline__ uint32_t pkbf(float a, float b) {
    // pack 2 floats -> 2 bf16 (RNE), low half = a (k even)
    uint32_t ua = __float_as_uint(a), ub = __float_as_uint(b);
    ua += 0x7fff + ((ua >> 16) & 1);
    ub += 0x7fff + ((ub >> 16) & 1);
    return (ua >> 16) | (ub & 0xffff0000u);
}

__global__ __launch_bounds__(NTHR, 4)
void corr_mfma_kernel(const float* __restrict__ f1,
                      const float* __restrict__ f2,
                      float* __restrict__ out)
{
    __shared__ uint32_t lds[2 * BUFW];   // 62976 B

    const int t    = threadIdx.x;
    const int wy   = t >> 6;             // wave id = local y (0..7)
    const int lane = t & 63;
    const int nn   = lane & 15;          // MFMA col (n) / frag row id
    const int qq   = lane >> 4;          // quad (k-group / D row group)

    const int bid = blockIdx.x;
    const int img = bid & 7;             // XCD-pinned image
    const int tr  = bid >> 3;            // 0..199
    const int y0  = (tr / 20) * YT;
    const int x0  = (tr % 20) * XT;
    const int phase = img;               // all blocks of an image share chunk order

    const float* f1n = f1 + (size_t)img * C_ * HW_;
    const float* f2n = f2 + (size_t)img * C_ * HW_;

    // ---------- staging maps (per thread, chunk-invariant) ----------
    // A: thread u -> c-pair pA (k=2pA,2pA+1), row ayA (0..7), x-quad mqA (0..3)
    const int pA  = t & 15;
    const int ayA = (t >> 4) & 7;
    const int mqA = t >> 7;
    const int xA  = x0 + 4 * mqA;                  // 16B-aligned; full-quad OOB only
    const bool vA = (xA + 3) < W_;                 // x0<=152 so OOB quads are full
    const int offA = 2 * pA * HW_ + (y0 + ayA) * W_ + (vA ? xA : 0);
    const int awrd = ayA * ROWW + (4 * mqA) * KLINE + pA;

    // B: thread u -> c-pair pB, source-row s (0..15), n-half nqB (0..1)
    const int pB  = t & 15;
    const int nqB = (t >> 4) & 1;
    const int sB  = t >> 5;
    const int ysB = y0 + sB - MAXD;
    const bool rowok = (unsigned)ysB < (unsigned)H_;
    const int xB0 = x0 - MAXD + 8 * nqB;           // 16B-aligned (x0%8==0)
    bool vB[2]; int offB[2];
#pragma unroll
    for (int tq = 0; tq < 2; ++tq) {
        const int xq = xB0 + 4 * tq;               // quad fully in- or out-of-bounds
        vB[tq] = rowok && (xq >= 0) && ((xq + 3) < W_);
        offB[tq] = 2 * pB * HW_ + (rowok ? ysB * W_ : 0) + (vB[tq] ? xq : 0);
    }
    const int bwrd = AW + sB * ROWW + (8 * nqB) * KLINE + pB;

    // ---------- fragment read offsets (words) ----------
    const int afrag_w = wy * ROWW + nn * KLINE + 4 * qq;        // A: wave's y row
    const int bfrag_base = AW + wy * ROWW + nn * KLINE + 4 * qq; // + dy*ROWW

    frag_cd acc[9];
#pragma unroll
    for (int d = 0; d < 9; ++d) acc[d] = (frag_cd){0.f, 0.f, 0.f, 0.f};

    // offB[tq] already includes the x offset — NO extra +4*tq here (R3 bug)
#define LOADS(c0, ra, rb)                                                     \
    {                                                                         \
        const int ca = (c0) * HW_;                                            \
        ra[0] = vA ? *(const float4*)(f1n + ca + offA) : float4{0,0,0,0};     \
        ra[1] = vA ? *(const float4*)(f1n + ca + offA + HW_) : float4{0,0,0,0};\
        _Pragma("unroll")                                                     \
        for (int tq = 0; tq < 2; ++tq) {                                      \
            rb[tq]     = vB[tq] ? *(const float4*)(f2n + ca + offB[tq])       \
                                : float4{0,0,0,0};                            \
            rb[tq + 2] = vB[tq] ? *(const float4*)(f2n + ca + offB[tq] + HW_) \
                                : float4{0,0,0,0};                            \
        }                                                                     \
    }

#define WRITES(buf, ra, rb)                                                   \
    {                                                                         \
        uint32_t* wp = lds + (buf) * BUFW;                                    \
        const float* a0 = (const float*)&ra[0];                               \
        const float* a1 = (const float*)&ra[1];                               \
        _Pragma("unroll")                                                     \
        for (int i = 0; i < 4; ++i)                                           \
            wp[awrd + i * KLINE] = pkbf(a0[i], a1[i]);                        \
        _Pragma("unroll")                                                     \
        for (int tq = 0; tq < 2; ++tq) {                                      \
            const float* b0 = (const float*)&rb[tq];                          \
            const float* b1 = (const float*)&rb[tq + 2];                      \
            _Pragma("unroll")                                                 \
            for (int i = 0; i < 4; ++i)                                       \
                wp[bwrd + (4 * tq + i) * KLINE] = pkbf(b0[i], b1[i]);         \
        }                                                                     \
    }

    float4 ra[2], rb[4];

    // prologue: stage first chunk
    LOADS(((phase) & 7) * KC, ra, rb);
    WRITES(0, ra, rb);
    __syncthreads();

    for (int i = 0; i < NCH; ++i) {
        const int p = i & 1;

        // issue next chunk's global loads first (age across the MFMA section)
        if (i + 1 < NCH) LOADS((((i + 1 + phase) & 7) * KC), ra, rb);

        const uint32_t* rp = lds + p * BUFW;
        const frag_ab af = *(const frag_ab*)(rp + afrag_w);
#pragma unroll
        for (int d = 0; d < 9; ++d) {
            const frag_ab bf = *(const frag_ab*)(rp + bfrag_base + d * ROWW);
            acc[d] = __builtin_amdgcn_mfma_f32_16x16x32_bf16(af, bf, acc[d], 0, 0, 0);
        }

        if (i + 1 < NCH) WRITES(1 - p, ra, rb);
        __syncthreads();
    }

    // ---------- epilogue: band extract, scale, leaky, store ----------
    const float inv_c = 1.0f / (float)C_;
    const int y = y0 + wy;
#pragma unroll
    for (int d = 0; d < 9; ++d) {
#pragma unroll
        for (int r = 0; r < 4; ++r) {
            const int m  = 4 * qq + r;        // D row = output x - x0
            const int dx = nn - m;
            if (m < XT && (unsigned)dx <= 8u) {
                float e = acc[d][r] * inv_c;
                e = e > 0.0f ? e : 0.1f * e;
                const int ch = d * 9 + dx;
                out[((size_t)(img * 81 + ch) * H_ + y) * W_ + (x0 + m)] = e;
            }
        }
    }
}

extern "C" void kernel_launch(void* const* d_in, const int* in_sizes, int n_in,
                              void* d_out, int out_size, void* d_ws, size_t ws_size,
                              hipStream_t stream) {
    const float* f1 = (const float*)d_in[0];
    const float* f2 = (const float*)d_in[1];
    float* out = (float*)d_out;
    const int nblocks = N_ * (H_ / YT) * (W_ / XT);  // 8*10*20 = 1600
    corr_mfma_kernel<<<dim3(nblocks), dim3(NTHR), 0, stream>>>(f1, f2, out);
}